// Round 31
// baseline (798.951 us; speedup 1.0000x reference)
//
#include <hip/hip_runtime.h>
#include <hip/hip_bf16.h>
#include <cstdint>

// Problem constants (match reference)
#define M_TOK 8192
#define K_IN  4096
#define N_OUT 11008
#define NP8   (N_OUT / 8)
#define GS    128

// DTYPE CONTRACT (verified round 4): x/scales/bias/out are float32 on device;
// qweight/qzeros are int32.

typedef __attribute__((ext_vector_type(8)))  short  s16x8;
typedef __attribute__((ext_vector_type(8)))  __bf16 bf16x8;
typedef __attribute__((ext_vector_type(4)))  float  f32x4;
typedef __attribute__((ext_vector_type(16))) float  f32x16;

// ---------------------------------------------------------------------------
__global__ __launch_bounds__(256) void convert_x_kernel(
    const float* __restrict__ in, unsigned short* __restrict__ outp, long n8)
{
    long i = (long)blockIdx.x * blockDim.x + threadIdx.x;
    const long stride = (long)gridDim.x * blockDim.x;
    for (; i < n8; i += stride) {
        const float4 a = ((const float4*)in)[2 * i];
        const float4 b = ((const float4*)in)[2 * i + 1];
        bf16x8 h;
        h[0] = (__bf16)a.x; h[1] = (__bf16)a.y; h[2] = (__bf16)a.z; h[3] = (__bf16)a.w;
        h[4] = (__bf16)b.x; h[5] = (__bf16)b.y; h[6] = (__bf16)b.z; h[7] = (__bf16)b.w;
        ((int4*)outp)[i] = __builtin_bit_cast(int4, h);
    }
}

// ---------------------------------------------------------------------------
__global__ __launch_bounds__(256) void dequant_kernel(
    const unsigned int* __restrict__ qw,
    const unsigned int* __restrict__ qz,
    const float*        __restrict__ sc,
    unsigned short*     __restrict__ wt,
    int n_base)
{
    const int tid = threadIdx.x;
    const int k8  = tid & 15;
    const int n8  = tid >> 4;
    const int g   = blockIdx.x;
    const int k0  = g * GS + k8 * 8;
    const int ncl = blockIdx.y * 128 + n8 * 8;
    const int ng  = n_base + ncl;
    const int j8  = ng >> 3;

    const unsigned int z = qz[(size_t)g * NP8 + j8];

    float s[8];
    *(float4*)&s[0] = *(const float4*)&sc[(size_t)g * N_OUT + ng];
    *(float4*)&s[4] = *(const float4*)&sc[(size_t)g * N_OUT + ng + 4];

    unsigned int q[8];
#pragma unroll
    for (int i = 0; i < 8; i++) q[i] = qw[(size_t)(k0 + i) * NP8 + j8];

#pragma unroll
    for (int t = 0; t < 8; t++) {
        const float sf  = s[t];
        const float nzs = -(float)((z >> (4 * t)) & 0xFu) * sf;
        bf16x8 h;
#pragma unroll
        for (int i = 0; i < 8; i++) {
            const float nib = (float)((q[i] >> (4 * t)) & 0xFu);
            h[i] = (__bf16)fmaf(nib, sf, nzs);
        }
        *(int4*)&wt[(size_t)(ncl + t) * K_IN + k0] = __builtin_bit_cast(int4, h);
    }
}

// ---------------------------------------------------------------------------
// FINAL (verified 9x: 794-830 us total, ~940 TF GEMM, MfmaUtil 43-46%,
// SQ_LDS_BANK_CONFLICT = 0, no spill, absmax 0.125; 4.4x vs first pass).
// 8-phase 256x256 skeleton, BK=64, 8 waves (2M x 4N), 32x32x16 MFMA.
// OCTET-EXTENDED T2 swizzle: chunk = c ^ (row&7) ^ ((row>>3)&3), applied
// inverse on the global_load_lds source and forward on ds_read (rule 21) —
// eliminates the 4-way {l,l+8,l+16,l+24} bank collision of 32-lane rows.
// Phase p reads A quad p (read-ahead, AX/AY ping-pong); B read all-at-gate;
// stages 2 units/phase issued 4-7 phases ahead; gates = counted vmcnt(6)
// (provably the unique correct counted wait; shallower collapses HBM MLP:
// r20 -28%). T1 bijective XCD swizzle; T5 setprio around MFMA clusters;
// m101 32x32 C/D epilogue layout.
// ---------------------------------------------------------------------------
#define GLOAD16(gp, lp)                                                        \
    __builtin_amdgcn_global_load_lds(                                          \
        (const __attribute__((address_space(1))) void*)(gp),                   \
        (__attribute__((address_space(3))) void*)(lp), 16, 0, 0)

__global__ __launch_bounds__(512, 1) void gemm_8pw_kernel(
    const unsigned short* __restrict__ A,     // xb [M][K] bf16
    const unsigned short* __restrict__ Bt,    // wt chunk [nc][K] bf16
    const float*          __restrict__ bias,  // [N] f32
    float*                __restrict__ C,     // [M][N] f32
    int n_base)
{
    __shared__ __align__(16) unsigned short Alds[2][4][64 * 64];   // 64 KB
    __shared__ __align__(16) unsigned short Blds[2][2][128 * 64];  // 64 KB

    const int tid = threadIdx.x;
    const int l   = tid & 63;
    const int w   = tid >> 6;       // wave 0..7
    const int wm  = w >> 2;         // 0..1
    const int wn  = w & 3;          // 0..3

    // --- bijective XCD swizzle (m204)
    const int nwg = gridDim.x;
    const int q8  = nwg >> 3, r8 = nwg & 7;
    const int xcd = blockIdx.x & 7, idx = blockIdx.x >> 3;
    const int swz = ((xcd < r8) ? xcd * (q8 + 1) : r8 * (q8 + 1) + (xcd - r8) * q8) + idx;
    const int mtile = swz & 31;
    const int ntile = swz >> 5;

    const size_t blockM = (size_t)mtile * 256;
    const int    colc   = ntile * 256;

    const unsigned short* Ag = A  + blockM * K_IN;
    const unsigned short* Bg = Bt + (size_t)colc * K_IN;

    // --- staging roles; octet-extended inverse swizzle
    const int srow = tid >> 3;
    const int cch  = tid & 7;
    const int kcs  = cch ^ (srow & 7) ^ ((srow >> 3) & 3);
    const size_t agrow = (size_t)((srow >> 5) * 128 + (srow & 31)) * K_IN + kcs * 8;
    const size_t bgrow = (size_t)srow * K_IN + kcs * 8;

#define STG_A(par_, qd_, step_)                                                \
    GLOAD16(Ag + agrow + (size_t)(32 * (qd_)) * K_IN + (size_t)(step_) * 64,   \
            &Alds[par_][qd_][(w * 8) * 64])
#define STG_B(par_, hf_, pt_, step_)                                           \
    GLOAD16(Bg + bgrow + (size_t)((hf_) * 128 + (pt_) * 64) * K_IN             \
               + (size_t)(step_) * 64,                                         \
            &Blds[par_][hf_][((pt_) * 64 + w * 8) * 64])

    // --- compute roles (32x32x16); octet-extended forward swizzle
    const int ln31  = l & 31;
    const int kh    = l >> 5;               // 0..1: k = ks*16 + kh*8 + e
    const int bhalf = wn >> 1;
    int ach[4];
#pragma unroll
    for (int ks = 0; ks < 4; ks++)
        ach[ks] = (((ks * 2 + kh) ^ (l & 7) ^ ((ln31 >> 3) & 3))) * 8;
    const int arow = (wm * 32 + ln31) * 64;           // row-in-quarter
    int brow[2];
#pragma unroll
    for (int nb = 0; nb < 2; nb++)
        brow[nb] = ((wn & 1) * 64 + nb * 32 + ln31) * 64;

    s16x8 AX[4], AY[4], Bf[4][2];
    f32x16 acc[4][2];
#pragma unroll
    for (int i = 0; i < 4; i++)
#pragma unroll
        for (int j = 0; j < 2; j++)
#pragma unroll
            for (int e = 0; e < 16; e++) acc[i][j][e] = 0.f;

#define RD_A(dst, par_, mb_)                                                   \
    do { _Pragma("unroll")                                                     \
        for (int ks = 0; ks < 4; ks++)                                         \
            dst[ks] = *(const s16x8*)&Alds[par_][mb_][arow + ach[ks]];         \
    } while (0)
#define RD_B(par_)                                                             \
    do { _Pragma("unroll")                                                     \
        for (int ks = 0; ks < 4; ks++)                                         \
            _Pragma("unroll")                                                  \
            for (int nb = 0; nb < 2; nb++)                                     \
                Bf[ks][nb] = *(const s16x8*)&Blds[par_][bhalf][brow[nb] + ach[ks]]; \
    } while (0)
#define MF(mb_, ASET)                                                          \
    do { __builtin_amdgcn_s_setprio(1);                                        \
        _Pragma("unroll")                                                      \
        for (int ks = 0; ks < 4; ks++)                                         \
            _Pragma("unroll")                                                  \
            for (int nb = 0; nb < 2; nb++)                                     \
                acc[mb_][nb] = __builtin_amdgcn_mfma_f32_32x32x16_bf16(        \
                    __builtin_bit_cast(bf16x8, ASET[ks]),                      \
                    __builtin_bit_cast(bf16x8, Bf[ks][nb]),                    \
                    acc[mb_][nb], 0, 0, 0);                                    \
        __builtin_amdgcn_s_setprio(0); } while (0)

#define BARR() __builtin_amdgcn_s_barrier()
#define SGB()  __builtin_amdgcn_sched_barrier(0)

    const int NT = K_IN / 64;   // 64 K-steps
    const int NI = NT / 2;      // 32 iterations

    // Prologue: s0 all 8 units; s1 first 6.
    STG_A(0, 0, 0); STG_A(0, 1, 0); STG_A(0, 2, 0); STG_A(0, 3, 0);
    STG_B(0, 0, 0, 0); STG_B(0, 0, 1, 0); STG_B(0, 1, 0, 0); STG_B(0, 1, 1, 0);
    STG_A(1, 0, 1); STG_A(1, 1, 1); STG_A(1, 2, 1);
    STG_B(1, 0, 0, 1); STG_B(1, 0, 1, 1); STG_B(1, 1, 0, 1);

    // gate0 (par0): s0 resident when only s1's 6 remain outstanding.
    asm volatile("s_waitcnt vmcnt(6)" ::: "memory");
    BARR(); SGB();
    RD_B(0); RD_A(AX, 0, 0);
    STG_A(1, 3, 1); STG_B(1, 1, 1, 1);
    BARR();

    for (int i = 0; i < NI; ++i) {
        const int s2 = 2 * i + 2, s3 = 2 * i + 3;
        const bool t2 = s2 < NT, t3 = s3 < NT;

        // ph1: read A q1; stage Aq0+Bp00 (s2); MFMA mb0
        RD_A(AY, 0, 1);
        if (t2) { STG_A(0, 0, s2); STG_B(0, 0, 0, s2); }
        BARR();
        MF(0, AX);
        // ph2
        RD_A(AX, 0, 2);
        if (t2) { STG_A(0, 1, s2); STG_B(0, 0, 1, s2); }
        BARR();
        MF(1, AY);
        // ph3
        RD_A(AY, 0, 3);
        if (t2) { STG_A(0, 2, s2); STG_B(0, 1, 0, s2); }
        BARR();
        MF(2, AX);
        // ph4 (gate par1): MFMA mb3 of par0 FIRST (frees Bf), then reload
        if (i < NI - 1) asm volatile("s_waitcnt vmcnt(6)" ::: "memory");
        else            asm volatile("s_waitcnt vmcnt(0)" ::: "memory");
        BARR(); SGB();
        MF(3, AY);
        RD_B(1); RD_A(AX, 1, 0);
        if (t2) { STG_A(0, 3, s2); STG_B(0, 1, 1, s2); }
        BARR();
        // ph5
        RD_A(AY, 1, 1);
        if (t3) { STG_A(1, 0, s3); STG_B(1, 0, 0, s3); }
        BARR();
        MF(0, AX);
        // ph6
        RD_A(AX, 1, 2);
        if (t3) { STG_A(1, 1, s3); STG_B(1, 0, 1, s3); }
        BARR();
        MF(1, AY);
        // ph7
        RD_A(AY, 1, 3);
        if (t3) { STG_A(1, 2, s3); STG_B(1, 1, 0, s3); }
        BARR();
        MF(2, AX);
        // ph0' (primes next iter): gate par0; MFMA mb3 of par1; reads; tail
        if (i < NI - 1) {
            asm volatile("s_waitcnt vmcnt(6)" ::: "memory");
            BARR(); SGB();
            MF(3, AY);
            RD_B(0); RD_A(AX, 0, 0);
            STG_A(1, 3, s3); STG_B(1, 1, 1, s3);
            BARR();
        }
    }
    // final: mb3 of the last par1 K-step
    MF(3, AY);
#undef STG_A
#undef STG_B
#undef RD_A
#undef RD_B
#undef MF
#undef BARR
#undef SGB

    // Epilogue: 32x32 C/D layout (m101): col = lane&31,
    // row = (reg&3) + 8*(reg>>2) + 4*(lane>>5)
#pragma unroll
    for (int nb = 0; nb < 2; ++nb) {
        const int ng = n_base + colc + wn * 64 + nb * 32 + ln31;
        const float bv = bias[ng];
#pragma unroll
        for (int mb = 0; mb < 4; ++mb) {
            f32x16 v = acc[mb][nb];
#pragma unroll
            for (int r = 0; r < 16; r++) {
                const int rowin = (r & 3) + 8 * (r >> 2) + 4 * kh;
                const size_t grow = blockM + wm * 128 + mb * 32 + rowin;
                C[grow * N_OUT + ng] = v[r] + bv;
            }
        }
    }
}

// ---------------------------------------------------------------------------
// Fallback: fully fused kernel (passed round 4, verbatim).
// ---------------------------------------------------------------------------
__global__ __launch_bounds__(256) void fused_w4a16_kernel(
    const float*        __restrict__ A,
    const unsigned int* __restrict__ qw,
    const unsigned int* __restrict__ qz,
    const float*        __restrict__ sc,
    const float*        __restrict__ bias,
    float*              __restrict__ C)
{
    __shared__ __align__(16) unsigned short As[128 * 64];
    __shared__ __align__(16) unsigned short Bs[128 * 64];

    const int tid = threadIdx.x;
    const int l   = tid & 63;
    const int w   = tid >> 6;
    const int wm  = w >> 1;
    const int wn  = w & 1;
    const size_t blockM = (size_t)blockIdx.x * 128;
    const int    colN   = blockIdx.y * 128;

    const float* Ag = A + blockM * K_IN;

    const int r_in = l >> 3;
    const int cch  = l & 7;
    int    aw_off[4];
    size_t ag_off[4];
#pragma unroll
    for (int qq = 0; qq < 4; qq++) {
        const int row = w * 32 + qq * 8 + r_in;
        aw_off[qq] = row * 64 + ((cch ^ r_in) * 8);
        ag_off[qq] = (size_t)row * K_IN + cch * 8;
    }

    const int kc = tid & 7;
    int ngl[4], j8[4], shn[4], bs_off[4];
#pragma unroll
    for (int p = 0; p < 4; p++) {
        const int nl = p * 32 + (tid >> 3);
        const int ng = colN + nl;
        ngl[p]    = ng;
        j8[p]     = ng >> 3;
        shn[p]    = 4 * (ng & 7);
        bs_off[p] = nl * 64 + ((kc ^ (nl & 7)) * 8);
    }

    f32x4 acc[4][4];
#pragma unroll
    for (int i = 0; i < 4; i++)
#pragma unroll
        for (int j = 0; j < 4; j++) acc[i][j] = (f32x4){0.f, 0.f, 0.f, 0.f};

    const int lrow = l & 15;
    const int lk   = l >> 4;
    const int NT   = K_IN / 64;

    for (int kt = 0; kt < NT; ++kt) {
        const int K0 = kt * 64;
        const int g  = K0 >> 7;

        float4 fa[4][2];
#pragma unroll
        for (int qq = 0; qq < 4; qq++) {
            fa[qq][0] = *(const float4*)(Ag + ag_off[qq] + K0);
            fa[qq][1] = *(const float4*)(Ag + ag_off[qq] + K0 + 4);
        }

        unsigned int q[4][8];
        float sf[4], nzs[4];
#pragma unroll
        for (int p = 0; p < 4; p++) {
            const unsigned int* qp = qw + (size_t)(K0 + kc * 8) * NP8 + j8[p];
#pragma unroll
            for (int i = 0; i < 8; i++) q[p][i] = qp[(size_t)i * NP8];
            const float zf = (float)((qz[(size_t)g * NP8 + j8[p]] >> shn[p]) & 0xFu);
            sf[p]  = sc[(size_t)g * N_OUT + ngl[p]];
            nzs[p] = -zf * sf[p];
        }

        __syncthreads();

#pragma unroll
        for (int qq = 0; qq < 4; qq++) {
            bf16x8 h;
#pragma unroll
            for (int i = 0; i < 4; i++) {
                h[i]     = (__bf16)(((const float*)&fa[qq][0])[i]);
                h[i + 4] = (__bf16)(((const float*)&fa[qq][1])[i]);
            }
            *(int4*)&As[aw_off[qq]] = __builtin_bit_cast(int4, h);
        }
#pragma unroll
        for (int p = 0; p < 4; p++) {
            bf16x8 h;
#pragma unroll
            for (int i = 0; i < 8; i++) {
                const float nib = (float)((q[p][i] >> shn[p]) & 0xFu);
                h[i] = (__bf16)fmaf(nib, sf[p], nzs[p]);
            }
            *(int4*)&Bs[bs_off[p]] = __builtin_bit_cast(int4, h);
        }

        __syncthreads();

#pragma unroll
        for (int ks = 0; ks < 2; ++ks) {
            s16x8 a[4], b[4];
            const int kcc = ks * 4 + lk;
#pragma unroll
            for (int mi = 0; mi < 4; mi++) {
                const int row = wm * 64 + mi * 16 + lrow;
                a[mi] = *(const s16x8*)&As[row * 64 + ((kcc ^ (row & 7)) * 8)];
            }
#pragma unroll
            for (int ni = 0; ni < 4; ni++) {
                const int row = wn * 64 + ni * 16 + lrow;
                b[ni] = *(const s16x8*)&Bs[row * 64 + ((kcc ^ (row & 7)) * 8)];
            }
#pragma unroll
            for (int mi = 0; mi < 4; mi++)
#pragma unroll
                for (int ni = 0; ni < 4; ni++)
                    acc[mi][ni] = __builtin_amdgcn_mfma_f32_16x16x32_bf16(
                        __builtin_bit_cast(bf16x8, a[mi]),
                        __builtin_bit_cast(bf16x8, b[ni]),
                        acc[mi][ni], 0, 0, 0);
        }
    }

#pragma unroll
    for (int ni = 0; ni < 4; ++ni) {
        const int ng = colN + wn * 64 + ni * 16 + lrow;
        const float bv = bias[ng];
#pragma unroll
        for (int mi = 0; mi < 4; ++mi) {
            f32x4 v = acc[mi][ni];
#pragma unroll
            for (int r = 0; r < 4; r++) {
                const size_t grow = blockM + wm * 64 + mi * 16 + lk * 4 + r;
                C[grow * N_OUT + ng] = v[r] + bv;
            }
        }
    }
}

// ---------------------------------------------------------------------------
extern "C" void kernel_launch(void* const* d_in, const int* in_sizes, int n_in,
                              void* d_out, int out_size, void* d_ws, size_t ws_size,
                              hipStream_t stream)
{
    const float*        x    = (const float*)d_in[0];
    const unsigned int* qw   = (const unsigned int*)d_in[1];
    const unsigned int* qz   = (const unsigned int*)d_in[2];
    const float*        sc   = (const float*)d_in[3];
    const float*        bias = (const float*)d_in[4];
    float*              out  = (float*)d_out;

    const size_t XBF    = (size_t)M_TOK * K_IN * 2;   // 64 MiB bf16 x
    const size_t COL256 = (size_t)256 * K_IN * 2;     // 2 MiB per 256 cols W^T

    if (ws_size >= XBF + COL256) {
        unsigned short* xb = (unsigned short*)d_ws;
        unsigned short* wt = (unsigned short*)((char*)d_ws + XBF);
        const long n8 = (long)M_TOK * K_IN / 8;
        convert_x_kernel<<<2048, 256, 0, stream>>>(x, xb, n8);

        size_t chunk_cols = ((ws_size - XBF) / COL256) * 256;
        if (chunk_cols > (size_t)N_OUT) chunk_cols = N_OUT;
        for (int n0 = 0; n0 < N_OUT; n0 += (int)chunk_cols) {
            int nc = N_OUT - n0;
            if (nc > (int)chunk_cols) nc = (int)chunk_cols;
            dequant_kernel<<<dim3(K_IN / GS, nc / 128), 256, 0, stream>>>(qw, qz, sc, wt, n0);
            gemm_8pw_kernel<<<32 * (nc / 256), 512, 0, stream>>>(xb, wt, bias, out, n0);
        }
    } else {
        fused_w4a16_kernel<<<dim3(M_TOK / 128, N_OUT / 128), 256, 0, stream>>>(
            x, qw, qz, sc, bias, out);
    }
}

// Round 32
// 793.442 us; speedup vs baseline: 1.0069x; 1.0069x over previous
//
#include <hip/hip_runtime.h>
#include <hip/hip_bf16.h>
#include <cstdint>

// Problem constants (match reference)
#define M_TOK 8192
#define K_IN  4096
#define N_OUT 11008
#define NP8   (N_OUT / 8)
#define GS    128

// DTYPE CONTRACT (verified round 4): x/scales/bias/out are float32 on device;
// qweight/qzeros are int32.

typedef __attribute__((ext_vector_type(8)))  short  s16x8;
typedef __attribute__((ext_vector_type(8)))  __bf16 bf16x8;
typedef __attribute__((ext_vector_type(4)))  float  f32x4;
typedef __attribute__((ext_vector_type(16))) float  f32x16;

// ---------------------------------------------------------------------------
__global__ __launch_bounds__(256) void convert_x_kernel(
    const float* __restrict__ in, unsigned short* __restrict__ outp, long n8)
{
    long i = (long)blockIdx.x * blockDim.x + threadIdx.x;
    const long stride = (long)gridDim.x * blockDim.x;
    for (; i < n8; i += stride) {
        const float4 a = ((const float4*)in)[2 * i];
        const float4 b = ((const float4*)in)[2 * i + 1];
        bf16x8 h;
        h[0] = (__bf16)a.x; h[1] = (__bf16)a.y; h[2] = (__bf16)a.z; h[3] = (__bf16)a.w;
        h[4] = (__bf16)b.x; h[5] = (__bf16)b.y; h[6] = (__bf16)b.z; h[7] = (__bf16)b.w;
        ((int4*)outp)[i] = __builtin_bit_cast(int4, h);
    }
}

// ---------------------------------------------------------------------------
__global__ __launch_bounds__(256) void dequant_kernel(
    const unsigned int* __restrict__ qw,
    const unsigned int* __restrict__ qz,
    const float*        __restrict__ sc,
    unsigned short*     __restrict__ wt,
    int n_base)
{
    const int tid = threadIdx.x;
    const int k8  = tid & 15;
    const int n8  = tid >> 4;
    const int g   = blockIdx.x;
    const int k0  = g * GS + k8 * 8;
    const int ncl = blockIdx.y * 128 + n8 * 8;
    const int ng  = n_base + ncl;
    const int j8  = ng >> 3;

    const unsigned int z = qz[(size_t)g * NP8 + j8];

    float s[8];
    *(float4*)&s[0] = *(const float4*)&sc[(size_t)g * N_OUT + ng];
    *(float4*)&s[4] = *(const float4*)&sc[(size_t)g * N_OUT + ng + 4];

    unsigned int q[8];
#pragma unroll
    for (int i = 0; i < 8; i++) q[i] = qw[(size_t)(k0 + i) * NP8 + j8];

#pragma unroll
    for (int t = 0; t < 8; t++) {
        const float sf  = s[t];
        const float nzs = -(float)((z >> (4 * t)) & 0xFu) * sf;
        bf16x8 h;
#pragma unroll
        for (int i = 0; i < 8; i++) {
            const float nib = (float)((q[i] >> (4 * t)) & 0xFu);
            h[i] = (__bf16)fmaf(nib, sf, nzs);
        }
        *(int4*)&wt[(size_t)(ncl + t) * K_IN + k0] = __builtin_bit_cast(int4, h);
    }
}

// ---------------------------------------------------------------------------
// FINAL (verified 10x: 794-830 us total, ~940 TF GEMM, MfmaUtil 42-46%,
// SQ_LDS_BANK_CONFLICT = 0, no spill, absmax 0.125; 4.4x vs first pass).
// 8-phase 256x256 skeleton, BK=64, 8 waves (2M x 4N), 32x32x16 MFMA.
// OCTET-EXTENDED T2 swizzle: chunk = c ^ (row&7) ^ ((row>>3)&3), applied
// inverse on the global_load_lds source and forward on ds_read (rule 21) —
// eliminates the 4-way {l,l+8,l+16,l+24} bank collision of 32-lane rows.
// Phase p reads A quad p (read-ahead, AX/AY ping-pong); B read all-at-gate;
// stages 2 units/phase issued 4-7 phases ahead; gates = counted vmcnt(6)
// (provably the unique correct counted wait; shallower collapses HBM MLP:
// r20 -28%). T1 bijective XCD swizzle; T5 setprio around MFMA clusters;
// m101 32x32 C/D epilogue layout.
// ---------------------------------------------------------------------------
#define GLOAD16(gp, lp)                                                        \
    __builtin_amdgcn_global_load_lds(                                          \
        (const __attribute__((address_space(1))) void*)(gp),                   \
        (__attribute__((address_space(3))) void*)(lp), 16, 0, 0)

__global__ __launch_bounds__(512, 1) void gemm_8pw_kernel(
    const unsigned short* __restrict__ A,     // xb [M][K] bf16
    const unsigned short* __restrict__ Bt,    // wt chunk [nc][K] bf16
    const float*          __restrict__ bias,  // [N] f32
    float*                __restrict__ C,     // [M][N] f32
    int n_base)
{
    __shared__ __align__(16) unsigned short Alds[2][4][64 * 64];   // 64 KB
    __shared__ __align__(16) unsigned short Blds[2][2][128 * 64];  // 64 KB

    const int tid = threadIdx.x;
    const int l   = tid & 63;
    const int w   = tid >> 6;       // wave 0..7
    const int wm  = w >> 2;         // 0..1
    const int wn  = w & 3;          // 0..3

    // --- bijective XCD swizzle (m204)
    const int nwg = gridDim.x;
    const int q8  = nwg >> 3, r8 = nwg & 7;
    const int xcd = blockIdx.x & 7, idx = blockIdx.x >> 3;
    const int swz = ((xcd < r8) ? xcd * (q8 + 1) : r8 * (q8 + 1) + (xcd - r8) * q8) + idx;
    const int mtile = swz & 31;
    const int ntile = swz >> 5;

    const size_t blockM = (size_t)mtile * 256;
    const int    colc   = ntile * 256;

    const unsigned short* Ag = A  + blockM * K_IN;
    const unsigned short* Bg = Bt + (size_t)colc * K_IN;

    // --- staging roles; octet-extended inverse swizzle
    const int srow = tid >> 3;
    const int cch  = tid & 7;
    const int kcs  = cch ^ (srow & 7) ^ ((srow >> 3) & 3);
    const size_t agrow = (size_t)((srow >> 5) * 128 + (srow & 31)) * K_IN + kcs * 8;
    const size_t bgrow = (size_t)srow * K_IN + kcs * 8;

#define STG_A(par_, qd_, step_)                                                \
    GLOAD16(Ag + agrow + (size_t)(32 * (qd_)) * K_IN + (size_t)(step_) * 64,   \
            &Alds[par_][qd_][(w * 8) * 64])
#define STG_B(par_, hf_, pt_, step_)                                           \
    GLOAD16(Bg + bgrow + (size_t)((hf_) * 128 + (pt_) * 64) * K_IN             \
               + (size_t)(step_) * 64,                                         \
            &Blds[par_][hf_][((pt_) * 64 + w * 8) * 64])

    // --- compute roles (32x32x16); octet-extended forward swizzle
    const int ln31  = l & 31;
    const int kh    = l >> 5;               // 0..1: k = ks*16 + kh*8 + e
    const int bhalf = wn >> 1;
    int ach[4];
#pragma unroll
    for (int ks = 0; ks < 4; ks++)
        ach[ks] = (((ks * 2 + kh) ^ (l & 7) ^ ((ln31 >> 3) & 3))) * 8;
    const int arow = (wm * 32 + ln31) * 64;           // row-in-quarter
    int brow[2];
#pragma unroll
    for (int nb = 0; nb < 2; nb++)
        brow[nb] = ((wn & 1) * 64 + nb * 32 + ln31) * 64;

    s16x8 AX[4], AY[4], Bf[4][2];
    f32x16 acc[4][2];
#pragma unroll
    for (int i = 0; i < 4; i++)
#pragma unroll
        for (int j = 0; j < 2; j++)
#pragma unroll
            for (int e = 0; e < 16; e++) acc[i][j][e] = 0.f;

#define RD_A(dst, par_, mb_)                                                   \
    do { _Pragma("unroll")                                                     \
        for (int ks = 0; ks < 4; ks++)                                         \
            dst[ks] = *(const s16x8*)&Alds[par_][mb_][arow + ach[ks]];         \
    } while (0)
#define RD_B(par_)                                                             \
    do { _Pragma("unroll")                                                     \
        for (int ks = 0; ks < 4; ks++)                                         \
            _Pragma("unroll")                                                  \
            for (int nb = 0; nb < 2; nb++)                                     \
                Bf[ks][nb] = *(const s16x8*)&Blds[par_][bhalf][brow[nb] + ach[ks]]; \
    } while (0)
#define MF(mb_, ASET)                                                          \
    do { __builtin_amdgcn_s_setprio(1);                                        \
        _Pragma("unroll")                                                      \
        for (int ks = 0; ks < 4; ks++)                                         \
            _Pragma("unroll")                                                  \
            for (int nb = 0; nb < 2; nb++)                                     \
                acc[mb_][nb] = __builtin_amdgcn_mfma_f32_32x32x16_bf16(        \
                    __builtin_bit_cast(bf16x8, ASET[ks]),                      \
                    __builtin_bit_cast(bf16x8, Bf[ks][nb]),                    \
                    acc[mb_][nb], 0, 0, 0);                                    \
        __builtin_amdgcn_s_setprio(0); } while (0)

#define BARR() __builtin_amdgcn_s_barrier()
#define SGB()  __builtin_amdgcn_sched_barrier(0)

    const int NT = K_IN / 64;   // 64 K-steps
    const int NI = NT / 2;      // 32 iterations

    // Prologue: s0 all 8 units; s1 first 6.
    STG_A(0, 0, 0); STG_A(0, 1, 0); STG_A(0, 2, 0); STG_A(0, 3, 0);
    STG_B(0, 0, 0, 0); STG_B(0, 0, 1, 0); STG_B(0, 1, 0, 0); STG_B(0, 1, 1, 0);
    STG_A(1, 0, 1); STG_A(1, 1, 1); STG_A(1, 2, 1);
    STG_B(1, 0, 0, 1); STG_B(1, 0, 1, 1); STG_B(1, 1, 0, 1);

    // gate0 (par0): s0 resident when only s1's 6 remain outstanding.
    asm volatile("s_waitcnt vmcnt(6)" ::: "memory");
    BARR(); SGB();
    RD_B(0); RD_A(AX, 0, 0);
    STG_A(1, 3, 1); STG_B(1, 1, 1, 1);
    BARR();

    for (int i = 0; i < NI; ++i) {
        const int s2 = 2 * i + 2, s3 = 2 * i + 3;
        const bool t2 = s2 < NT, t3 = s3 < NT;

        // ph1: read A q1; stage Aq0+Bp00 (s2); MFMA mb0
        RD_A(AY, 0, 1);
        if (t2) { STG_A(0, 0, s2); STG_B(0, 0, 0, s2); }
        BARR();
        MF(0, AX);
        // ph2
        RD_A(AX, 0, 2);
        if (t2) { STG_A(0, 1, s2); STG_B(0, 0, 1, s2); }
        BARR();
        MF(1, AY);
        // ph3
        RD_A(AY, 0, 3);
        if (t2) { STG_A(0, 2, s2); STG_B(0, 1, 0, s2); }
        BARR();
        MF(2, AX);
        // ph4 (gate par1): MFMA mb3 of par0 FIRST (frees Bf), then reload
        if (i < NI - 1) asm volatile("s_waitcnt vmcnt(6)" ::: "memory");
        else            asm volatile("s_waitcnt vmcnt(0)" ::: "memory");
        BARR(); SGB();
        MF(3, AY);
        RD_B(1); RD_A(AX, 1, 0);
        if (t2) { STG_A(0, 3, s2); STG_B(0, 1, 1, s2); }
        BARR();
        // ph5
        RD_A(AY, 1, 1);
        if (t3) { STG_A(1, 0, s3); STG_B(1, 0, 0, s3); }
        BARR();
        MF(0, AX);
        // ph6
        RD_A(AX, 1, 2);
        if (t3) { STG_A(1, 1, s3); STG_B(1, 0, 1, s3); }
        BARR();
        MF(1, AY);
        // ph7
        RD_A(AY, 1, 3);
        if (t3) { STG_A(1, 2, s3); STG_B(1, 1, 0, s3); }
        BARR();
        MF(2, AX);
        // ph0' (primes next iter): gate par0; MFMA mb3 of par1; reads; tail
        if (i < NI - 1) {
            asm volatile("s_waitcnt vmcnt(6)" ::: "memory");
            BARR(); SGB();
            MF(3, AY);
            RD_B(0); RD_A(AX, 0, 0);
            STG_A(1, 3, s3); STG_B(1, 1, 1, s3);
            BARR();
        }
    }
    // final: mb3 of the last par1 K-step
    MF(3, AY);
#undef STG_A
#undef STG_B
#undef RD_A
#undef RD_B
#undef MF
#undef BARR
#undef SGB

    // Epilogue: 32x32 C/D layout (m101): col = lane&31,
    // row = (reg&3) + 8*(reg>>2) + 4*(lane>>5)
#pragma unroll
    for (int nb = 0; nb < 2; ++nb) {
        const int ng = n_base + colc + wn * 64 + nb * 32 + ln31;
        const float bv = bias[ng];
#pragma unroll
        for (int mb = 0; mb < 4; ++mb) {
            f32x16 v = acc[mb][nb];
#pragma unroll
            for (int r = 0; r < 16; r++) {
                const int rowin = (r & 3) + 8 * (r >> 2) + 4 * kh;
                const size_t grow = blockM + wm * 128 + mb * 32 + rowin;
                C[grow * N_OUT + ng] = v[r] + bv;
            }
        }
    }
}

// ---------------------------------------------------------------------------
// Fallback: fully fused kernel (passed round 4, verbatim).
// ---------------------------------------------------------------------------
__global__ __launch_bounds__(256) void fused_w4a16_kernel(
    const float*        __restrict__ A,
    const unsigned int* __restrict__ qw,
    const unsigned int* __restrict__ qz,
    const float*        __restrict__ sc,
    const float*        __restrict__ bias,
    float*              __restrict__ C)
{
    __shared__ __align__(16) unsigned short As[128 * 64];
    __shared__ __align__(16) unsigned short Bs[128 * 64];

    const int tid = threadIdx.x;
    const int l   = tid & 63;
    const int w   = tid >> 6;
    const int wm  = w >> 1;
    const int wn  = w & 1;
    const size_t blockM = (size_t)blockIdx.x * 128;
    const int    colN   = blockIdx.y * 128;

    const float* Ag = A + blockM * K_IN;

    const int r_in = l >> 3;
    const int cch  = l & 7;
    int    aw_off[4];
    size_t ag_off[4];
#pragma unroll
    for (int qq = 0; qq < 4; qq++) {
        const int row = w * 32 + qq * 8 + r_in;
        aw_off[qq] = row * 64 + ((cch ^ r_in) * 8);
        ag_off[qq] = (size_t)row * K_IN + cch * 8;
    }

    const int kc = tid & 7;
    int ngl[4], j8[4], shn[4], bs_off[4];
#pragma unroll
    for (int p = 0; p < 4; p++) {
        const int nl = p * 32 + (tid >> 3);
        const int ng = colN + nl;
        ngl[p]    = ng;
        j8[p]     = ng >> 3;
        shn[p]    = 4 * (ng & 7);
        bs_off[p] = nl * 64 + ((kc ^ (nl & 7)) * 8);
    }

    f32x4 acc[4][4];
#pragma unroll
    for (int i = 0; i < 4; i++)
#pragma unroll
        for (int j = 0; j < 4; j++) acc[i][j] = (f32x4){0.f, 0.f, 0.f, 0.f};

    const int lrow = l & 15;
    const int lk   = l >> 4;
    const int NT   = K_IN / 64;

    for (int kt = 0; kt < NT; ++kt) {
        const int K0 = kt * 64;
        const int g  = K0 >> 7;

        float4 fa[4][2];
#pragma unroll
        for (int qq = 0; qq < 4; qq++) {
            fa[qq][0] = *(const float4*)(Ag + ag_off[qq] + K0);
            fa[qq][1] = *(const float4*)(Ag + ag_off[qq] + K0 + 4);
        }

        unsigned int q[4][8];
        float sf[4], nzs[4];
#pragma unroll
        for (int p = 0; p < 4; p++) {
            const unsigned int* qp = qw + (size_t)(K0 + kc * 8) * NP8 + j8[p];
#pragma unroll
            for (int i = 0; i < 8; i++) q[p][i] = qp[(size_t)i * NP8];
            const float zf = (float)((qz[(size_t)g * NP8 + j8[p]] >> shn[p]) & 0xFu);
            sf[p]  = sc[(size_t)g * N_OUT + ngl[p]];
            nzs[p] = -zf * sf[p];
        }

        __syncthreads();

#pragma unroll
        for (int qq = 0; qq < 4; qq++) {
            bf16x8 h;
#pragma unroll
            for (int i = 0; i < 4; i++) {
                h[i]     = (__bf16)(((const float*)&fa[qq][0])[i]);
                h[i + 4] = (__bf16)(((const float*)&fa[qq][1])[i]);
            }
            *(int4*)&As[aw_off[qq]] = __builtin_bit_cast(int4, h);
        }
#pragma unroll
        for (int p = 0; p < 4; p++) {
            bf16x8 h;
#pragma unroll
            for (int i = 0; i < 8; i++) {
                const float nib = (float)((q[p][i] >> shn[p]) & 0xFu);
                h[i] = (__bf16)fmaf(nib, sf[p], nzs[p]);
            }
            *(int4*)&Bs[bs_off[p]] = __builtin_bit_cast(int4, h);
        }

        __syncthreads();

#pragma unroll
        for (int ks = 0; ks < 2; ++ks) {
            s16x8 a[4], b[4];
            const int kcc = ks * 4 + lk;
#pragma unroll
            for (int mi = 0; mi < 4; mi++) {
                const int row = wm * 64 + mi * 16 + lrow;
                a[mi] = *(const s16x8*)&As[row * 64 + ((kcc ^ (row & 7)) * 8)];
            }
#pragma unroll
            for (int ni = 0; ni < 4; ni++) {
                const int row = wn * 64 + ni * 16 + lrow;
                b[ni] = *(const s16x8*)&Bs[row * 64 + ((kcc ^ (row & 7)) * 8)];
            }
#pragma unroll
            for (int mi = 0; mi < 4; mi++)
#pragma unroll
                for (int ni = 0; ni < 4; ni++)
                    acc[mi][ni] = __builtin_amdgcn_mfma_f32_16x16x32_bf16(
                        __builtin_bit_cast(bf16x8, a[mi]),
                        __builtin_bit_cast(bf16x8, b[ni]),
                        acc[mi][ni], 0, 0, 0);
        }
    }

#pragma unroll
    for (int ni = 0; ni < 4; ++ni) {
        const int ng = colN + wn * 64 + ni * 16 + lrow;
        const float bv = bias[ng];
#pragma unroll
        for (int mi = 0; mi < 4; ++mi) {
            f32x4 v = acc[mi][ni];
#pragma unroll
            for (int r = 0; r < 4; r++) {
                const size_t grow = blockM + wm * 64 + mi * 16 + lk * 4 + r;
                C[grow * N_OUT + ng] = v[r] + bv;
            }
        }
    }
}

// ---------------------------------------------------------------------------
extern "C" void kernel_launch(void* const* d_in, const int* in_sizes, int n_in,
                              void* d_out, int out_size, void* d_ws, size_t ws_size,
                              hipStream_t stream)
{
    const float*        x    = (const float*)d_in[0];
    const unsigned int* qw   = (const unsigned int*)d_in[1];
    const unsigned int* qz   = (const unsigned int*)d_in[2];
    const float*        sc   = (const float*)d_in[3];
    const float*        bias = (const float*)d_in[4];
    float*              out  = (float*)d_out;

    const size_t XBF    = (size_t)M_TOK * K_IN * 2;   // 64 MiB bf16 x
    const size_t COL256 = (size_t)256 * K_IN * 2;     // 2 MiB per 256 cols W^T

    if (ws_size >= XBF + COL256) {
        unsigned short* xb = (unsigned short*)d_ws;
        unsigned short* wt = (unsigned short*)((char*)d_ws + XBF);
        const long n8 = (long)M_TOK * K_IN / 8;
        convert_x_kernel<<<2048, 256, 0, stream>>>(x, xb, n8);

        size_t chunk_cols = ((ws_size - XBF) / COL256) * 256;
        if (chunk_cols > (size_t)N_OUT) chunk_cols = N_OUT;
        for (int n0 = 0; n0 < N_OUT; n0 += (int)chunk_cols) {
            int nc = N_OUT - n0;
            if (nc > (int)chunk_cols) nc = (int)chunk_cols;
            dequant_kernel<<<dim3(K_IN / GS, nc / 128), 256, 0, stream>>>(qw, qz, sc, wt, n0);
            gemm_8pw_kernel<<<32 * (nc / 256), 512, 0, stream>>>(xb, wt, bias, out, n0);
        }
    } else {
        fused_w4a16_kernel<<<dim3(M_TOK / 128, N_OUT / 128), 256, 0, stream>>>(
            x, qw, qz, sc, bias, out);
    }
}